// Round 1
// baseline (247.462 us; speedup 1.0000x reference)
//
#include <hip/hip_runtime.h>
#include <hip/hip_bf16.h>
#include <cstdint>

typedef unsigned short u16;
typedef __attribute__((ext_vector_type(4))) float f32x4;
typedef __attribute__((ext_vector_type(8))) short s16x8;
typedef __attribute__((ext_vector_type(4))) unsigned int u32x4;

#define B_    2
#define LQ_   2048
#define LKV_  2048
#define C_    1024
#define CTX_  768
#define H_    16
#define DK_   64
#define SCALE_ 0.125f

__device__ __forceinline__ u16 f2b(float f) {
  union { float f; unsigned int u; } v; v.f = f;
  unsigned int r = v.u + 0x7fffu + ((v.u >> 16) & 1u);
  return (u16)(r >> 16);
}

// ---------------- elementwise cast fp32 -> bf16 ----------------
__global__ void cast_bf16(const float* __restrict__ in, u16* __restrict__ out, int n) {
  int i = (blockIdx.x * 256 + threadIdx.x) * 4;
  if (i + 3 >= n + 3) return;
  if (i >= n) return;
  float4 v = *reinterpret_cast<const float4*>(in + i);
  ushort4 r;
  r.x = f2b(v.x); r.y = f2b(v.y); r.z = f2b(v.z); r.w = f2b(v.w);
  *reinterpret_cast<ushort4*>(out + i) = r;
}

// ---------------- transpose + cast: W[K][N] f32 -> WT[N][K] bf16 ----------------
__global__ void transpose_cast(const float* __restrict__ W, u16* __restrict__ WT, int K, int N) {
  __shared__ u16 tile[64][65];
  const int t = threadIdx.x;
  const int n0 = blockIdx.x * 64, k0 = blockIdx.y * 64;
#pragma unroll
  for (int p = 0; p < 4; ++p) {
    int r = (t >> 4) + p * 16;       // k within tile
    int c = (t & 15) * 4;            // n within tile
    float4 v = *reinterpret_cast<const float4*>(W + (size_t)(k0 + r) * N + n0 + c);
    tile[r][c + 0] = f2b(v.x);
    tile[r][c + 1] = f2b(v.y);
    tile[r][c + 2] = f2b(v.z);
    tile[r][c + 3] = f2b(v.w);
  }
  __syncthreads();
#pragma unroll
  for (int p = 0; p < 4; ++p) {
    int nr = (t >> 4) + p * 16;      // n within tile
    int kc = (t & 15) * 4;           // k within tile
    ushort4 o;
    o.x = tile[kc + 0][nr];
    o.y = tile[kc + 1][nr];
    o.z = tile[kc + 2][nr];
    o.w = tile[kc + 3][nr];
    *reinterpret_cast<ushort4*>(WT + (size_t)(n0 + nr) * K + k0 + kc) = o;
  }
}

// ---------------- GEMM: C[M,N] = A[M,K] * BT[N,K]^T (bf16 in, fp32 acc) ----------------
// OM==0: bf16 out; OM==1: fp32 out + bias
template <int OM>
__global__ __launch_bounds__(256, 2)
void gemm_bt(const u16* __restrict__ A, const u16* __restrict__ BT,
             u16* __restrict__ Cb, float* __restrict__ Cf,
             const float* __restrict__ bias, int M, int N, int K) {
  __shared__ u16 sA[128 * 32];
  __shared__ u16 sB[128 * 32];
  const int tid = threadIdx.x;
  const int w = tid >> 6, lane = tid & 63;
  const int l16 = lane & 15, lk = lane >> 4;
  const int m0 = blockIdx.x * 128, n0 = blockIdx.y * 128;
  const int wm = w >> 1, wn = w & 1;

  f32x4 acc[4][4];
#pragma unroll
  for (int i = 0; i < 4; ++i)
#pragma unroll
    for (int j = 0; j < 4; ++j)
      acc[i][j] = (f32x4){0.f, 0.f, 0.f, 0.f};

  // staging: wave w owns 32 rows of each tile; 2 instrs of 16 rows (lane: row=i>>2, kchunk=i&3)
  const u16* ga0 = A  + (size_t)(m0 + w * 32 + (lane >> 2)) * K + (lane & 3) * 8;
  const u16* ga1 = ga0 + (size_t)16 * K;
  const u16* gb0 = BT + (size_t)(n0 + w * 32 + (lane >> 2)) * K + (lane & 3) * 8;
  const u16* gb1 = gb0 + (size_t)16 * K;
  u16* la0 = sA + (w * 32) * 32;
  u16* la1 = la0 + 16 * 32;
  u16* lb0 = sB + (w * 32) * 32;
  u16* lb1 = lb0 + 16 * 32;

  for (int k0 = 0; k0 < K; k0 += 32) {
    __builtin_amdgcn_global_load_lds((const __attribute__((address_space(1))) void*)ga0,
                                     (__attribute__((address_space(3))) void*)la0, 16, 0, 0);
    __builtin_amdgcn_global_load_lds((const __attribute__((address_space(1))) void*)ga1,
                                     (__attribute__((address_space(3))) void*)la1, 16, 0, 0);
    __builtin_amdgcn_global_load_lds((const __attribute__((address_space(1))) void*)gb0,
                                     (__attribute__((address_space(3))) void*)lb0, 16, 0, 0);
    __builtin_amdgcn_global_load_lds((const __attribute__((address_space(1))) void*)gb1,
                                     (__attribute__((address_space(3))) void*)lb1, 16, 0, 0);
    ga0 += 32; ga1 += 32; gb0 += 32; gb1 += 32;
    __syncthreads();

    s16x8 af[4], bf[4];
#pragma unroll
    for (int mt = 0; mt < 4; ++mt)
      af[mt] = *reinterpret_cast<const s16x8*>(sA + (wm * 64 + mt * 16 + l16) * 32 + lk * 8);
#pragma unroll
    for (int nt = 0; nt < 4; ++nt)
      bf[nt] = *reinterpret_cast<const s16x8*>(sB + (wn * 64 + nt * 16 + l16) * 32 + lk * 8);
#pragma unroll
    for (int mt = 0; mt < 4; ++mt)
#pragma unroll
      for (int nt = 0; nt < 4; ++nt)
        acc[mt][nt] = __builtin_amdgcn_mfma_f32_16x16x32_bf16(af[mt], bf[nt], acc[mt][nt], 0, 0, 0);
    __syncthreads();
  }

#pragma unroll
  for (int mt = 0; mt < 4; ++mt) {
#pragma unroll
    for (int j = 0; j < 4; ++j) {
      int row = m0 + wm * 64 + mt * 16 + lk * 4 + j;
#pragma unroll
      for (int nt = 0; nt < 4; ++nt) {
        int col = n0 + wn * 64 + nt * 16 + l16;
        if (OM == 0) {
          Cb[(size_t)row * N + col] = f2b(acc[mt][nt][j]);
        } else {
          Cf[(size_t)row * N + col] = acc[mt][nt][j] + bias[col];
        }
      }
    }
  }
}

// ---------------- flash attention ----------------
// grid: (LQ/64, B*H); block 256 (4 waves, 16 q-rows each); KVBLK=64, D=64
__global__ __launch_bounds__(256, 2)
void flash_attn(const u16* __restrict__ Qb, const u16* __restrict__ KVb, u16* __restrict__ Rb) {
  __shared__ u16 sK[64 * 64];        // [j][d], XOR-swizzled rows
  __shared__ u16 sVT[64 * 64];       // [d][j], XOR-swizzled rows
  __shared__ u16 sP[4][16 * 64];     // per-wave P tile, XOR-swizzled rows

  const int tid = threadIdx.x;
  const int w = tid >> 6, lane = tid & 63;
  const int l16 = lane & 15, lk = lane >> 4;
  const int bh = blockIdx.y;
  const int b = bh >> 4, h = bh & 15;
  const int qrow0 = blockIdx.x * 64 + w * 16;

  // Q fragments in registers (A-frag: row = lane&15, k = (lane>>4)*8..)
  const u16* qptr = Qb + (size_t)(b * LQ_ + qrow0 + l16) * 1024 + h * 64;
  s16x8 qf0 = *reinterpret_cast<const s16x8*>(qptr + lk * 8);
  s16x8 qf1 = *reinterpret_cast<const s16x8*>(qptr + 32 + lk * 8);

  f32x4 Oacc[4];
  float m_run[4], d_run[4];
#pragma unroll
  for (int j = 0; j < 4; ++j) { m_run[j] = -1e30f; d_run[j] = 0.f; }
#pragma unroll
  for (int dt = 0; dt < 4; ++dt) Oacc[dt] = (f32x4){0.f, 0.f, 0.f, 0.f};

  const u16* Kb = KVb + (size_t)b * LKV_ * 2048 + h * 64;
  const u16* Vb = Kb + 1024;
  char* sKc = reinterpret_cast<char*>(sK);
  char* sVc = reinterpret_cast<char*>(sVT);
  char* sPc = reinterpret_cast<char*>(sP[w]);

  for (int jt = 0; jt < LKV_ / 64; ++jt) {
    // ---- stage K rows (swizzled) and V transposed (swizzled) ----
#pragma unroll
    for (int cc = 0; cc < 2; ++cc) {
      int c = tid + cc * 256;        // 512 chunks of 16B
      int row = c >> 3, ch = c & 7;
      u32x4 kv = *reinterpret_cast<const u32x4*>(Kb + (size_t)(jt * 64 + row) * 2048 + ch * 8);
      *reinterpret_cast<u32x4*>(sKc + row * 128 + ((ch * 16) ^ ((row & 7) << 4))) = kv;
      s16x8 vv = *reinterpret_cast<const s16x8*>(Vb + (size_t)(jt * 64 + row) * 2048 + ch * 8);
#pragma unroll
      for (int i = 0; i < 8; ++i) {
        int d = ch * 8 + i;
        *reinterpret_cast<u16*>(sVc + d * 128 + ((row * 2) ^ ((d & 7) << 4))) = (u16)vv[i];
      }
    }
    __syncthreads();

    // ---- S = Q K^T (rows: lk*4+j, cols: ct*16+l16) ----
    f32x4 sacc[4];
#pragma unroll
    for (int ct = 0; ct < 4; ++ct) {
      int jj = ct * 16 + l16;
      const char* kr = sKc + jj * 128;
      int sw = (jj & 7) << 4;
      s16x8 kb0 = *reinterpret_cast<const s16x8*>(kr + ((lk * 16) ^ sw));
      s16x8 kb1 = *reinterpret_cast<const s16x8*>(kr + ((64 + lk * 16) ^ sw));
      f32x4 z = (f32x4){0.f, 0.f, 0.f, 0.f};
      z = __builtin_amdgcn_mfma_f32_16x16x32_bf16(qf0, kb0, z, 0, 0, 0);
      z = __builtin_amdgcn_mfma_f32_16x16x32_bf16(qf1, kb1, z, 0, 0, 0);
      sacc[ct] = z;
    }

    // ---- online softmax (wave-parallel row reduce over 16 lanes) ----
#pragma unroll
    for (int j = 0; j < 4; ++j) {
      float mx = fmaxf(fmaxf(sacc[0][j], sacc[1][j]), fmaxf(sacc[2][j], sacc[3][j]));
#pragma unroll
      for (int s = 1; s < 16; s <<= 1) mx = fmaxf(mx, __shfl_xor(mx, s, 64));
      mx *= SCALE_;
      float mnew = fmaxf(m_run[j], mx);
      float sc = __expf(m_run[j] - mnew);
      m_run[j] = mnew;
      float ps = 0.f;
      int prow = lk * 4 + j;
      int swp = (prow & 7) << 4;
#pragma unroll
      for (int ct = 0; ct < 4; ++ct) {
        float pv = __expf(sacc[ct][j] * SCALE_ - mnew);
        ps += pv;
        int col = ct * 16 + l16;
        *reinterpret_cast<u16*>(sPc + prow * 128 + ((col * 2) ^ swp)) = f2b(pv);
      }
#pragma unroll
      for (int s = 1; s < 16; s <<= 1) ps += __shfl_xor(ps, s, 64);
      d_run[j] = d_run[j] * sc + ps;
#pragma unroll
      for (int dt = 0; dt < 4; ++dt) Oacc[dt][j] *= sc;
    }

    // ---- O += P V ----
    {
      const char* pr = sPc + l16 * 128;
      int sw = (l16 & 7) << 4;
      s16x8 pa0 = *reinterpret_cast<const s16x8*>(pr + ((lk * 16) ^ sw));
      s16x8 pa1 = *reinterpret_cast<const s16x8*>(pr + ((64 + lk * 16) ^ sw));
#pragma unroll
      for (int dt = 0; dt < 4; ++dt) {
        int d = dt * 16 + l16;
        const char* vr = sVc + d * 128;
        int swv = (d & 7) << 4;
        s16x8 vb0 = *reinterpret_cast<const s16x8*>(vr + ((lk * 16) ^ swv));
        s16x8 vb1 = *reinterpret_cast<const s16x8*>(vr + ((64 + lk * 16) ^ swv));
        Oacc[dt] = __builtin_amdgcn_mfma_f32_16x16x32_bf16(pa0, vb0, Oacc[dt], 0, 0, 0);
        Oacc[dt] = __builtin_amdgcn_mfma_f32_16x16x32_bf16(pa1, vb1, Oacc[dt], 0, 0, 0);
      }
    }
    __syncthreads();
  }

  // ---- epilogue: res[b, i, h*64+d] = O / d_run ----
  u16* op = Rb + (size_t)(b * LQ_ + qrow0) * 1024 + h * 64;
#pragma unroll
  for (int j = 0; j < 4; ++j) {
    float inv = 1.f / d_run[j];
    int row = lk * 4 + j;
#pragma unroll
    for (int dt = 0; dt < 4; ++dt) {
      op[(size_t)row * 1024 + dt * 16 + l16] = f2b(Oacc[dt][j] * inv);
    }
  }
}

// ---------------- launch ----------------
extern "C" void kernel_launch(void* const* d_in, const int* in_sizes, int n_in,
                              void* d_out, int out_size, void* d_ws, size_t ws_size,
                              hipStream_t stream) {
  const float* x   = (const float*)d_in[0];   // [2,2048,1024]
  const float* y   = (const float*)d_in[1];   // [2,2048,768]
  const float* Wq  = (const float*)d_in[2];   // [1024,1024]
  const float* Wkv = (const float*)d_in[3];   // [768,2048]
  const float* Wp  = (const float*)d_in[4];   // [1024,1024]
  const float* bp  = (const float*)d_in[5];   // [1024]
  float* out = (float*)d_out;                 // [2,2048,1024]

  u16* p = (u16*)d_ws;
  u16* xb   = p; p += (size_t)4096 * 1024;
  u16* yb   = p; p += (size_t)4096 * 768;
  u16* WqT  = p; p += (size_t)1024 * 1024;
  u16* WkvT = p; p += (size_t)2048 * 768;
  u16* WpT  = p; p += (size_t)1024 * 1024;
  u16* Qb   = p; p += (size_t)4096 * 1024;
  u16* KVb  = p; p += (size_t)4096 * 2048;
  u16* Rb   = p; p += (size_t)4096 * 1024;

  cast_bf16<<<4096, 256, 0, stream>>>(x, xb, 4096 * 1024);
  cast_bf16<<<3072, 256, 0, stream>>>(y, yb, 4096 * 768);
  transpose_cast<<<dim3(16, 16), 256, 0, stream>>>(Wq, WqT, 1024, 1024);
  transpose_cast<<<dim3(32, 12), 256, 0, stream>>>(Wkv, WkvT, 768, 2048);
  transpose_cast<<<dim3(16, 16), 256, 0, stream>>>(Wp, WpT, 1024, 1024);

  // Q = x @ Wq : [4096,1024]
  gemm_bt<0><<<dim3(32, 8), 256, 0, stream>>>(xb, WqT, Qb, nullptr, nullptr, 4096, 1024, 1024);
  // KV = y @ Wkv : [4096,2048] (K = cols [0,1024), V = cols [1024,2048))
  gemm_bt<0><<<dim3(32, 16), 256, 0, stream>>>(yb, WkvT, KVb, nullptr, nullptr, 4096, 2048, 768);
  // attention -> Rb [4096,1024]
  flash_attn<<<dim3(32, 32), 256, 0, stream>>>(Qb, KVb, Rb);
  // out = Rb @ Wproj + bias : [4096,1024] fp32
  gemm_bt<1><<<dim3(32, 8), 256, 0, stream>>>(Rb, WpT, nullptr, out, bp, 4096, 1024, 1024);
}

// Round 2
// 170.118 us; speedup vs baseline: 1.4546x; 1.4546x over previous
//
#include <hip/hip_runtime.h>
#include <hip/hip_bf16.h>
#include <cstdint>

typedef unsigned short u16;
typedef __attribute__((ext_vector_type(4))) float f32x4;
typedef __attribute__((ext_vector_type(8))) short s16x8;
typedef __attribute__((ext_vector_type(4))) unsigned int u32x4;

#define B_    2
#define LQ_   2048
#define LKV_  2048
#define C_    1024
#define CTX_  768
#define H_    16
#define DK_   64
#define SCALE_ 0.125f

__device__ __forceinline__ u16 f2b(float f) {
  union { float f; unsigned int u; } v; v.f = f;
  unsigned int r = v.u + 0x7fffu + ((v.u >> 16) & 1u);
  return (u16)(r >> 16);
}

__device__ __forceinline__ unsigned cvtpk(float lo, float hi) {
  unsigned r;
  asm("v_cvt_pk_bf16_f32 %0, %1, %2" : "=v"(r) : "v"(lo), "v"(hi));
  return r;
}

// ---------------- elementwise cast fp32 -> bf16 ----------------
__global__ void cast_bf16(const float* __restrict__ in, u16* __restrict__ out, int n) {
  int i = (blockIdx.x * 256 + threadIdx.x) * 4;
  if (i >= n) return;
  float4 v = *reinterpret_cast<const float4*>(in + i);
  ushort4 r;
  r.x = f2b(v.x); r.y = f2b(v.y); r.z = f2b(v.z); r.w = f2b(v.w);
  *reinterpret_cast<ushort4*>(out + i) = r;
}

// ---------------- transpose + cast: W[K][N] f32 -> WT[N][K] bf16 ----------------
__global__ void transpose_cast(const float* __restrict__ W, u16* __restrict__ WT, int K, int N) {
  __shared__ u16 tile[64][65];
  const int t = threadIdx.x;
  const int n0 = blockIdx.x * 64, k0 = blockIdx.y * 64;
#pragma unroll
  for (int p = 0; p < 4; ++p) {
    int r = (t >> 4) + p * 16;
    int c = (t & 15) * 4;
    float4 v = *reinterpret_cast<const float4*>(W + (size_t)(k0 + r) * N + n0 + c);
    tile[r][c + 0] = f2b(v.x);
    tile[r][c + 1] = f2b(v.y);
    tile[r][c + 2] = f2b(v.z);
    tile[r][c + 3] = f2b(v.w);
  }
  __syncthreads();
#pragma unroll
  for (int p = 0; p < 4; ++p) {
    int nr = (t >> 4) + p * 16;
    int kc = (t & 15) * 4;
    ushort4 o;
    o.x = tile[kc + 0][nr];
    o.y = tile[kc + 1][nr];
    o.z = tile[kc + 2][nr];
    o.w = tile[kc + 3][nr];
    *reinterpret_cast<ushort4*>(WT + (size_t)(n0 + nr) * K + k0 + kc) = o;
  }
}

// ---------------- V transpose: KVb V-part -> VT[bh][d=64][kv=2048] ----------------
__global__ void v_transpose(const u16* __restrict__ KVb, u16* __restrict__ VT) {
  const int bh = blockIdx.y;
  const int b = bh >> 4, h = bh & 15;
  const int kv0 = blockIdx.x * 64;
  const u16* src = KVb + ((size_t)b * LKV_) * 2048 + 1024 + h * 64;
  u16* dst = VT + ((size_t)bh * 64) * 2048;
  const int t = threadIdx.x;
#pragma unroll
  for (int p = 0; p < 2; ++p) {
    int idx = p * 256 + t;
    int d = idx >> 3, ch = idx & 7;
    s16x8 o;
#pragma unroll
    for (int i = 0; i < 8; ++i)
      o[i] = (short)src[(size_t)(kv0 + ch * 8 + i) * 2048 + d];
    *reinterpret_cast<s16x8*>(dst + (size_t)d * 2048 + kv0 + ch * 8) = o;
  }
}

// ---------------- GEMM: C[M,N] = A[M,K] * BT[N,K]^T (bf16 in, fp32 acc) ----------------
template <int OM>
__global__ __launch_bounds__(256, 2)
void gemm_bt(const u16* __restrict__ A, const u16* __restrict__ BT,
             u16* __restrict__ Cb, float* __restrict__ Cf,
             const float* __restrict__ bias, int M, int N, int K) {
  __shared__ u16 sA[128 * 32];
  __shared__ u16 sB[128 * 32];
  const int tid = threadIdx.x;
  const int w = tid >> 6, lane = tid & 63;
  const int l16 = lane & 15, lk = lane >> 4;
  const int m0 = blockIdx.x * 128, n0 = blockIdx.y * 128;
  const int wm = w >> 1, wn = w & 1;

  f32x4 acc[4][4];
#pragma unroll
  for (int i = 0; i < 4; ++i)
#pragma unroll
    for (int j = 0; j < 4; ++j)
      acc[i][j] = (f32x4){0.f, 0.f, 0.f, 0.f};

  const u16* ga0 = A  + (size_t)(m0 + w * 32 + (lane >> 2)) * K + (lane & 3) * 8;
  const u16* ga1 = ga0 + (size_t)16 * K;
  const u16* gb0 = BT + (size_t)(n0 + w * 32 + (lane >> 2)) * K + (lane & 3) * 8;
  const u16* gb1 = gb0 + (size_t)16 * K;
  u16* la0 = sA + (w * 32) * 32;
  u16* la1 = la0 + 16 * 32;
  u16* lb0 = sB + (w * 32) * 32;
  u16* lb1 = lb0 + 16 * 32;

  for (int k0 = 0; k0 < K; k0 += 32) {
    __builtin_amdgcn_global_load_lds((const __attribute__((address_space(1))) void*)ga0,
                                     (__attribute__((address_space(3))) void*)la0, 16, 0, 0);
    __builtin_amdgcn_global_load_lds((const __attribute__((address_space(1))) void*)ga1,
                                     (__attribute__((address_space(3))) void*)la1, 16, 0, 0);
    __builtin_amdgcn_global_load_lds((const __attribute__((address_space(1))) void*)gb0,
                                     (__attribute__((address_space(3))) void*)lb0, 16, 0, 0);
    __builtin_amdgcn_global_load_lds((const __attribute__((address_space(1))) void*)gb1,
                                     (__attribute__((address_space(3))) void*)lb1, 16, 0, 0);
    ga0 += 32; ga1 += 32; gb0 += 32; gb1 += 32;
    __syncthreads();

    s16x8 af[4], bf[4];
#pragma unroll
    for (int mt = 0; mt < 4; ++mt)
      af[mt] = *reinterpret_cast<const s16x8*>(sA + (wm * 64 + mt * 16 + l16) * 32 + lk * 8);
#pragma unroll
    for (int nt = 0; nt < 4; ++nt)
      bf[nt] = *reinterpret_cast<const s16x8*>(sB + (wn * 64 + nt * 16 + l16) * 32 + lk * 8);
#pragma unroll
    for (int mt = 0; mt < 4; ++mt)
#pragma unroll
      for (int nt = 0; nt < 4; ++nt)
        acc[mt][nt] = __builtin_amdgcn_mfma_f32_16x16x32_bf16(af[mt], bf[nt], acc[mt][nt], 0, 0, 0);
    __syncthreads();
  }

#pragma unroll
  for (int mt = 0; mt < 4; ++mt) {
#pragma unroll
    for (int j = 0; j < 4; ++j) {
      int row = m0 + wm * 64 + mt * 16 + lk * 4 + j;
#pragma unroll
      for (int nt = 0; nt < 4; ++nt) {
        int col = n0 + wn * 64 + nt * 16 + l16;
        if (OM == 0) {
          Cb[(size_t)row * N + col] = f2b(acc[mt][nt][j]);
        } else {
          Cf[(size_t)row * N + col] = acc[mt][nt][j] + bias[col];
        }
      }
    }
  }
}

// ---------------- flash attention v2 ----------------
// 2 waves/block, 32 q-rows/wave (2 q-groups of 16), KVBLK=64, D=64.
// S^T = mfma(K_perm, Q^T): lane (l16,lk) slot (ct,j) = S[q=l16][kv(ct,4lk+j)]
// kv(ct,o) = 8*(o>>2) + 4*((ct&1)^((o>>2)&1)) + (o&3) + 32*(ct>>1)
// => lane's 16 slots are exactly kv = {8lk..8lk+7} u {32+8lk..32+8lk+7}: the PV
//    B-fragment needs NO cross-lane movement (selects + cvt_pk only).
// O^T = mfma(VT, P^T): lane holds O[q=l16][d = 16dt + 4lk + j].
__global__ __launch_bounds__(128)
void flash_attn(const u16* __restrict__ Qb, const u16* __restrict__ KVb,
                const u16* __restrict__ VT, u16* __restrict__ Rb) {
  __shared__ u16 sK[2][4096];   // [64 rows][128B], chunk c' holds global chunk c'^(row&7)
  __shared__ u16 sV[2][4096];

  const int tid = threadIdx.x;
  const int w = tid >> 6, l = tid & 63;
  const int l16 = l & 15, lk = l >> 4;

  // bijective XCD swizzle: 1024 blocks, 8 XCDs, 128 blocks each -> 4 heads/XCD
  const int bid = blockIdx.x;
  const int wg = ((bid & 7) << 7) | (bid >> 3);
  const int bx = wg & 31, bh = wg >> 5;
  const int b = bh >> 4, h = bh & 15;
  const int qrow0 = bx * 64 + w * 32;

  // Q B-fragments (col=q=l16, k=dk): held in registers for the whole kernel
  const u16* qp = Qb + ((size_t)(b * LQ_ + qrow0 + l16)) * 1024 + h * 64;
  s16x8 qf[2][2];
#pragma unroll
  for (int g = 0; g < 2; ++g)
#pragma unroll
    for (int ks = 0; ks < 2; ++ks)
      qf[g][ks] = *reinterpret_cast<const s16x8*>(qp + g * 16 * 1024 + ks * 32 + lk * 8);

  f32x4 Oacc[2][4];
  float m_run[2] = {-1e30f, -1e30f}, d_run[2] = {0.f, 0.f};
#pragma unroll
  for (int g = 0; g < 2; ++g)
#pragma unroll
    for (int dt = 0; dt < 4; ++dt) Oacc[g][dt] = (f32x4){0.f, 0.f, 0.f, 0.f};

  // staging constants (swizzled-source global_load_lds: linear LDS dest,
  // source chunk pre-XORed so LDS layout == row*128 + 16*(c ^ (row&7)))
  const int srow = l >> 3;
  const int scol = (l & 7) ^ srow;
  const u16* Kg = KVb + ((size_t)b * LKV_) * 2048 + h * 64;
  const u16* Vg = VT + ((size_t)bh * 64) * 2048;

  // QK A-frag row constants
  const int r0 = ((l16 >> 2) << 3) + (l16 & 3);
  const int xpar = (l16 >> 2) & 1;
  const int swv = (l16 & 7) << 4;

  auto stage = [&](int jt, int bb) {
#pragma unroll
    for (int t = 0; t < 4; ++t) {
      int row = w * 32 + t * 8 + srow;
      __builtin_amdgcn_global_load_lds(
          (const __attribute__((address_space(1))) void*)(Kg + ((size_t)(jt * 64 + row)) * 2048 + scol * 8),
          (__attribute__((address_space(3))) void*)(&sK[bb][(w * 256 + t * 64) * 8]), 16, 0, 0);
      __builtin_amdgcn_global_load_lds(
          (const __attribute__((address_space(1))) void*)(Vg + ((size_t)row) * 2048 + jt * 64 + scol * 8),
          (__attribute__((address_space(3))) void*)(&sV[bb][(w * 256 + t * 64) * 8]), 16, 0, 0);
    }
  };

  stage(0, 0);
  __syncthreads();

  int cur = 0;
  for (int jt = 0; jt < LKV_ / 64; ++jt) {
    if (jt < LKV_ / 64 - 1) stage(jt + 1, cur ^ 1);
    const char* kb = (const char*)sK[cur];
    const char* vb = (const char*)sV[cur];

    // ---- S^T = K_perm . Q^T ----
    f32x4 sacc[2][4];
#pragma unroll
    for (int g = 0; g < 2; ++g)
#pragma unroll
      for (int ct = 0; ct < 4; ++ct) sacc[g][ct] = (f32x4){0.f, 0.f, 0.f, 0.f};

    __builtin_amdgcn_s_setprio(1);
#pragma unroll
    for (int ct = 0; ct < 4; ++ct) {
      const int R = r0 + (((ct & 1) ^ xpar) << 2) + ((ct >> 1) << 5);
      const char* rp = kb + R * 128;
      const int sw = (R & 7) << 4;
      s16x8 ka0 = *reinterpret_cast<const s16x8*>(rp + ((lk * 16) ^ sw));
      s16x8 ka1 = *reinterpret_cast<const s16x8*>(rp + ((64 + lk * 16) ^ sw));
      sacc[0][ct] = __builtin_amdgcn_mfma_f32_16x16x32_bf16(ka0, qf[0][0], sacc[0][ct], 0, 0, 0);
      sacc[0][ct] = __builtin_amdgcn_mfma_f32_16x16x32_bf16(ka1, qf[0][1], sacc[0][ct], 0, 0, 0);
      sacc[1][ct] = __builtin_amdgcn_mfma_f32_16x16x32_bf16(ka0, qf[1][0], sacc[1][ct], 0, 0, 0);
      sacc[1][ct] = __builtin_amdgcn_mfma_f32_16x16x32_bf16(ka1, qf[1][1], sacc[1][ct], 0, 0, 0);
    }
    __builtin_amdgcn_s_setprio(0);

    // ---- online softmax: 16 in-lane values + 2 shfl over lk-lanes ----
#pragma unroll
    for (int g = 0; g < 2; ++g) {
      float mx = sacc[g][0][0];
#pragma unroll
      for (int ct = 0; ct < 4; ++ct)
#pragma unroll
        for (int j = 0; j < 4; ++j) mx = fmaxf(mx, sacc[g][ct][j]);
      mx = fmaxf(mx, __shfl_xor(mx, 16, 64));
      mx = fmaxf(mx, __shfl_xor(mx, 32, 64));
      float mnew = fmaxf(m_run[g], mx * SCALE_);
      float sc = __expf(m_run[g] - mnew);
      float ps = 0.f;
#pragma unroll
      for (int ct = 0; ct < 4; ++ct)
#pragma unroll
        for (int j = 0; j < 4; ++j) {
          float e = __expf(sacc[g][ct][j] * SCALE_ - mnew);
          sacc[g][ct][j] = e;
          ps += e;
        }
      ps += __shfl_xor(ps, 16, 64);
      ps += __shfl_xor(ps, 32, 64);
      d_run[g] = d_run[g] * sc + ps;
      m_run[g] = mnew;
#pragma unroll
      for (int dt = 0; dt < 4; ++dt) Oacc[g][dt] *= sc;
    }

    // ---- O^T += VT . P^T (P stays in registers) ----
    const bool sel = (lk & 1) != 0;
#pragma unroll
    for (int f = 0; f < 2; ++f) {
      s16x8 pf[2];
#pragma unroll
      for (int g = 0; g < 2; ++g) {
        f32x4 pA = sel ? sacc[g][2 * f + 1] : sacc[g][2 * f];
        f32x4 pB = sel ? sacc[g][2 * f] : sacc[g][2 * f + 1];
        union { unsigned u[4]; s16x8 v; } pk;
        pk.u[0] = cvtpk(pA[0], pA[1]);
        pk.u[1] = cvtpk(pA[2], pA[3]);
        pk.u[2] = cvtpk(pB[0], pB[1]);
        pk.u[3] = cvtpk(pB[2], pB[3]);
        pf[g] = pk.v;
      }
      __builtin_amdgcn_s_setprio(1);
#pragma unroll
      for (int dt = 0; dt < 4; ++dt) {
        const char* vrp = vb + (dt * 16 + l16) * 128;
        s16x8 va = *reinterpret_cast<const s16x8*>(vrp + ((f * 64 + lk * 16) ^ swv));
        Oacc[0][dt] = __builtin_amdgcn_mfma_f32_16x16x32_bf16(va, pf[0], Oacc[0][dt], 0, 0, 0);
        Oacc[1][dt] = __builtin_amdgcn_mfma_f32_16x16x32_bf16(va, pf[1], Oacc[1][dt], 0, 0, 0);
      }
      __builtin_amdgcn_s_setprio(0);
    }
    __syncthreads();
    cur ^= 1;
  }

  // ---- epilogue: O[q=l16][d=16dt+4lk+j] / d_run ----
  u16* op = Rb + ((size_t)(b * LQ_ + qrow0 + l16)) * 1024 + h * 64 + lk * 4;
#pragma unroll
  for (int g = 0; g < 2; ++g) {
    float inv = 1.f / d_run[g];
#pragma unroll
    for (int dt = 0; dt < 4; ++dt) {
      ushort4 o;
      o.x = f2b(Oacc[g][dt][0] * inv);
      o.y = f2b(Oacc[g][dt][1] * inv);
      o.z = f2b(Oacc[g][dt][2] * inv);
      o.w = f2b(Oacc[g][dt][3] * inv);
      *reinterpret_cast<ushort4*>(op + g * 16 * 1024 + dt * 16) = o;
    }
  }
}

// ---------------- launch ----------------
extern "C" void kernel_launch(void* const* d_in, const int* in_sizes, int n_in,
                              void* d_out, int out_size, void* d_ws, size_t ws_size,
                              hipStream_t stream) {
  const float* x   = (const float*)d_in[0];
  const float* y   = (const float*)d_in[1];
  const float* Wq  = (const float*)d_in[2];
  const float* Wkv = (const float*)d_in[3];
  const float* Wp  = (const float*)d_in[4];
  const float* bp  = (const float*)d_in[5];
  float* out = (float*)d_out;

  u16* p = (u16*)d_ws;
  u16* xb   = p; p += (size_t)4096 * 1024;   // dead after Q-GEMM; reused as VT
  u16* yb   = p; p += (size_t)4096 * 768;
  u16* WqT  = p; p += (size_t)1024 * 1024;
  u16* WkvT = p; p += (size_t)2048 * 768;
  u16* WpT  = p; p += (size_t)1024 * 1024;
  u16* Qb   = p; p += (size_t)4096 * 1024;
  u16* KVb  = p; p += (size_t)4096 * 2048;
  u16* Rb   = p; p += (size_t)4096 * 1024;
  u16* VTb  = xb;                            // [32][64][2048]

  cast_bf16<<<4096, 256, 0, stream>>>(x, xb, 4096 * 1024);
  cast_bf16<<<3072, 256, 0, stream>>>(y, yb, 4096 * 768);
  transpose_cast<<<dim3(16, 16), 256, 0, stream>>>(Wq, WqT, 1024, 1024);
  transpose_cast<<<dim3(32, 12), 256, 0, stream>>>(Wkv, WkvT, 768, 2048);
  transpose_cast<<<dim3(16, 16), 256, 0, stream>>>(Wp, WpT, 1024, 1024);

  gemm_bt<0><<<dim3(32, 8), 256, 0, stream>>>(xb, WqT, Qb, nullptr, nullptr, 4096, 1024, 1024);
  gemm_bt<0><<<dim3(32, 16), 256, 0, stream>>>(yb, WkvT, KVb, nullptr, nullptr, 4096, 2048, 768);
  v_transpose<<<dim3(32, 32), 256, 0, stream>>>(KVb, VTb);
  flash_attn<<<1024, 128, 0, stream>>>(Qb, KVb, VTb, Rb);
  gemm_bt<1><<<dim3(32, 8), 256, 0, stream>>>(Rb, WpT, nullptr, out, bp, 4096, 1024, 1024);
}